// Round 14
// baseline (59.797 us; speedup 1.0000x reference)
//
#include <hip/hip_runtime.h>
#include <math.h>

#define SEQ   4096
#define HD    64
#define NH    16
#define WHALF 256
#define QB    128    // queries per block = 8 waves x 16
#define KT    128    // keys staged per barrier
#define KSTR  72     // K plane d-stride (shorts): 144B rows -> b128 R/W at 8-phase bank floor
#define VSTR  136    // V plane key-stride (shorts): 272B rows -> b128 R/W at 8-phase bank floor
#define KPLANE (KT * KSTR)   // 9216 shorts
#define VPLANE (HD * VSTR)   // 8704 shorts
#define BUFSZ  (KPLANE + VPLANE)

typedef __attribute__((ext_vector_type(8))) __bf16 bf16x8;
typedef __attribute__((ext_vector_type(8))) short short8v;
typedef __attribute__((ext_vector_type(4))) float f32x4;

__device__ __forceinline__ short bf16bits(float x) {
    __bf16 b = (__bf16)x;            // RTN
    return __builtin_bit_cast(short, b);
}

#define MFMA32(A, B, C) __builtin_amdgcn_mfma_f32_16x16x32_bf16((A), (B), (C), 0, 0, 0)

#if __has_builtin(__builtin_amdgcn_exp2f)
#define EXP2F(x) __builtin_amdgcn_exp2f(x)
#else
#define EXP2F(x) __exp2f(x)
#endif

#define LDFRAG(dst, src) (dst) = __builtin_bit_cast(bf16x8, *reinterpret_cast<const short8v*>(src))

__global__ __launch_bounds__(512, 4)
void swa_mfma14_kernel(const float* __restrict__ q,
                       const float* __restrict__ k,
                       const float* __restrict__ v,
                       float* __restrict__ out) {
    // double-buffered: [buf][K plane | V plane] ; 71680 B total -> 2 blocks/CU
    __shared__ short smem[2 * BUFSZ];

    // ---- XCD-aware bijective swizzle: 512 blocks = 8 XCDs x 64; head-major chunks ----
    const int orig = blockIdx.x;
    const int work = ((orig & 7) << 6) + (orig >> 3);
    const int h    = work >> 5;
    const int q0   = (work & 31) * QB;

    const int t    = threadIdx.x;
    const int lane = t & 63;
    const int w    = t >> 6;             // wave 0..7
    const int n15  = lane & 15;
    const int g    = lane >> 4;          // 0..3
    const int qrow = q0 + w * 16 + n15;  // this lane's query

    // scores in log2 domain (fold 1/sqrt(64)*log2(e) into Q); NO max-shift:
    // softmax is shift-invariant and scores are O(10) in the log2 domain.
    const float SCALE = 0.125f * 1.44269504088896340736f;

    // ---- Q fragments (B-operand of S^T = K·Q^T), pre-scaled, plain bf16 ----
    bf16x8 qf0, qf1;
    {
        const float* qp = q + ((size_t)h * SEQ + qrow) * HD;
        const float4* pa4 = reinterpret_cast<const float4*>(qp + 8 * g);
        const float4* pb4 = reinterpret_cast<const float4*>(qp + 32 + 8 * g);
        float4 a0 = pa4[0], a1 = pa4[1], b0 = pb4[0], b1 = pb4[1];
        float xa[8] = {a0.x, a0.y, a0.z, a0.w, a1.x, a1.y, a1.z, a1.w};
        float xb[8] = {b0.x, b0.y, b0.z, b0.w, b1.x, b1.y, b1.z, b1.w};
        short8v qa8, qb8;
        #pragma unroll
        for (int j = 0; j < 8; ++j) {
            qa8[j] = bf16bits(xa[j] * SCALE);
            qb8[j] = bf16bits(xb[j] * SCALE);
        }
        qf0 = __builtin_bit_cast(bf16x8, qa8);
        qf1 = __builtin_bit_cast(bf16x8, qb8);
    }

    // ones A-fragment for the lsum MFMA (row 0 of A = ones): register constant
    bf16x8 ones8;
    {
        short8v o8;
        const short ov = (n15 == 0) ? (short)0x3F80 : (short)0;
        #pragma unroll
        for (int j = 0; j < 8; ++j) o8[j] = ov;
        ones8 = __builtin_bit_cast(bf16x8, o8);
    }

    f32x4 accO0 = (f32x4){0.f, 0.f, 0.f, 0.f};
    f32x4 accO1 = (f32x4){0.f, 0.f, 0.f, 0.f};
    f32x4 accO2 = (f32x4){0.f, 0.f, 0.f, 0.f};
    f32x4 accO3 = (f32x4){0.f, 0.f, 0.f, 0.f};
    f32x4 accL  = (f32x4){0.f, 0.f, 0.f, 0.f};   // lsum lands in reg 0 of g=0 lanes

    int k0 = q0 - WHALF;           if (k0 < 0) k0 = 0;
    int k1 = q0 + QB - 1 + WHALF;  if (k1 > SEQ - 1) k1 = SEQ - 1;
    const int nt = (k1 + 1 - k0) >> 7;   // whole 128-key tiles

    const int wqmin = q0 + w * 16;
    const int wqmax = wqmin + 15;
    const int wlo   = wqmin - WHALF;   // wave union window
    const int whi   = wqmax + WHALF;

    const float4* kb4 = reinterpret_cast<const float4*>(k + ((size_t)h * SEQ) * HD);
    const float*  vp  = v + ((size_t)h * SEQ) * HD;

    // ---- single-set 2-tile-deep register prefetch (R10-proven codegen form) ----
    float4 kreg[4];
    float  vreg[16];

    #define LOADT(KTV)                                                        \
        {                                                                     \
            const int kt_ = (KTV);                                            \
            _Pragma("unroll")                                                 \
            for (int i2 = 0; i2 < 4; ++i2)                                    \
                kreg[i2] = kb4[(size_t)kt_ * 16 + t * 4 + i2];                \
            _Pragma("unroll")                                                 \
            for (int j = 0; j < 16; ++j)                                      \
                vreg[j] = vp[(size_t)(kt_ + 16 * w + j) * HD + lane];         \
        }

    // ---- stage regs -> buffer b.  K rows PERMUTED (within each 32-key chunk)
    // so the QK D-fragment hands each lane keys 8g..8g+7 (K=32 PV B-order):
    // physical key p: R = (p & 96) | perm5(p & 31), perm5 validated since R7.
    auto STAGE = [&](int b) {
        short* Kb = smem + b * BUFSZ;
        short* Vb = Kb + KPLANE;

        const int p  = t >> 2;           // physical key row (0..127); 4 threads/row
        const int q5 = p & 31;
        const int R  = (p & 96) + (((q5 >> 2) & 1) << 4) + ((q5 >> 3) << 2) + (q5 & 3);

        const float* kf = reinterpret_cast<const float*>(&kreg[0]);
        short8v k8a, k8b;
        #pragma unroll
        for (int j = 0; j < 8; ++j) {
            k8a[j] = bf16bits(kf[j]);
            k8b[j] = bf16bits(kf[8 + j]);
        }
        *reinterpret_cast<short8v*>(&Kb[R * KSTR + (t & 3) * 16])     = k8a;
        *reinterpret_cast<short8v*>(&Kb[R * KSTR + (t & 3) * 16 + 8]) = k8b;

        short8v v8a, v8b;
        #pragma unroll
        for (int j = 0; j < 8; ++j) {
            v8a[j] = bf16bits(vreg[j]);
            v8b[j] = bf16bits(vreg[8 + j]);
        }
        *reinterpret_cast<short8v*>(&Vb[lane * VSTR + 16 * w])     = v8a;  // [d=lane][key 16w..]
        *reinterpret_cast<short8v*>(&Vb[lane * VSTR + 16 * w + 8]) = v8b;
    };

    // ---- pipelined fragment load/compute macros (named regs, no arrays) ----
    #define LDK(p0a, p0b, p1a, p1b, KC)                                       \
        {                                                                     \
            const int _r0 = ((KC) * 32 + n15) * KSTR + 8 * g;                 \
            const int _r1 = ((KC) * 32 + 16 + n15) * KSTR + 8 * g;            \
            LDFRAG(p0a, &Kb[_r0]); LDFRAG(p0b, &Kb[_r0 + 32]);                \
            LDFRAG(p1a, &Kb[_r1]); LDFRAG(p1b, &Kb[_r1 + 32]);                \
        }

    #define LDV(KC)                                                           \
        {                                                                     \
            const int _vc = (KC) * 32 + 8 * g;                                \
            LDFRAG(vf0, &Vb[(n15) * VSTR + _vc]);                             \
            LDFRAG(vf1, &Vb[(16 + n15) * VSTR + _vc]);                        \
            LDFRAG(vf2, &Vb[(32 + n15) * VSTR + _vc]);                        \
            LDFRAG(vf3, &Vb[(48 + n15) * VSTR + _vc]);                        \
        }

    #define BODYN(p0a, p0b, p1a, p1b)                                         \
        {                                                                     \
            f32x4 _z = (f32x4){0.f, 0.f, 0.f, 0.f};                           \
            __builtin_amdgcn_s_setprio(1);                                    \
            f32x4 S0 = MFMA32(p0a, qf0, _z); S0 = MFMA32(p0b, qf1, S0);       \
            f32x4 S1 = MFMA32(p1a, qf0, _z); S1 = MFMA32(p1b, qf1, S1);       \
            __builtin_amdgcn_s_setprio(0);                                    \
            short8v p8s;                                                      \
            p8s[0] = bf16bits(EXP2F(S0[0])); p8s[1] = bf16bits(EXP2F(S0[1])); \
            p8s[2] = bf16bits(EXP2F(S0[2])); p8s[3] = bf16bits(EXP2F(S0[3])); \
            p8s[4] = bf16bits(EXP2F(S1[0])); p8s[5] = bf16bits(EXP2F(S1[1])); \
            p8s[6] = bf16bits(EXP2F(S1[2])); p8s[7] = bf16bits(EXP2F(S1[3])); \
            bf16x8 _p8 = __builtin_bit_cast(bf16x8, p8s);                     \
            __builtin_amdgcn_s_setprio(1);                                    \
            accO0 = MFMA32(vf0, _p8, accO0); accO1 = MFMA32(vf1, _p8, accO1); \
            accO2 = MFMA32(vf2, _p8, accO2); accO3 = MFMA32(vf3, _p8, accO3); \
            accL  = MFMA32(ones8, _p8, accL);                                 \
            __builtin_amdgcn_s_setprio(0);                                    \
        }

    LOADT(k0);
    STAGE(0);
    if (nt > 1) LOADT(k0 + KT);
    __syncthreads();

    for (int i = 0; i < nt; ++i) {
        const int kt  = k0 + i * KT;
        const int cur = i & 1;

        const short* Kb = smem + cur * BUFSZ;
        const short* Vb = Kb + KPLANE;

        const bool nomask = (kt >= wqmax - WHALF) && (kt + KT - 1 <= wqmin + WHALF);

        bf16x8 ka0a, ka0b, ka1a, ka1b, kb0a, kb0b, kb1a, kb1b;
        bf16x8 vf0, vf1, vf2, vf3;

        if (nomask) LDK(ka0a, ka0b, ka1a, ka1b, 0);   // issue earliest; hides under staging

        if (i + 1 < nt) {
            STAGE(cur ^ 1);
            if (i + 2 < nt) LOADT(k0 + (i + 2) * KT);
        }

        if (nomask) {
            // ---- cross-chunk register pipeline: K one chunk ahead, V early ----
            LDV(0); LDK(kb0a, kb0b, kb1a, kb1b, 1); BODYN(ka0a, ka0b, ka1a, ka1b);
            LDV(1); LDK(ka0a, ka0b, ka1a, ka1b, 2); BODYN(kb0a, kb0b, kb1a, kb1b);
            LDV(2); LDK(kb0a, kb0b, kb1a, kb1b, 3); BODYN(ka0a, ka0b, ka1a, ka1b);
            LDV(3);                                 BODYN(kb0a, kb0b, kb1a, kb1b);
        } else {
            #pragma unroll
            for (int kc = 0; kc < 4; ++kc) {
                const int cb = kt + kc * 32;
                if (cb > whi || cb + 31 < wlo) continue;   // wave-uniform chunk skip

                // ---- S^T = K·Q^T (two chained 16x16x32 per 16-key half) ----
                f32x4 S[2];
                __builtin_amdgcn_s_setprio(1);
                #pragma unroll
                for (int s = 0; s < 2; ++s) {
                    const int krow = (kc * 32 + s * 16 + n15) * KSTR + 8 * g;
                    bf16x8 k0f, k1f;
                    LDFRAG(k0f, &Kb[krow]);
                    LDFRAG(k1f, &Kb[krow + 32]);
                    f32x4 a = (f32x4){0.f, 0.f, 0.f, 0.f};
                    a = MFMA32(k0f, qf0, a);
                    a = MFMA32(k1f, qf1, a);
                    S[s] = a;
                }
                __builtin_amdgcn_s_setprio(0);

                // lane's 8 scores are keys cb+8g .. cb+8g+7
                short8v p8s;
                const bool interior = (cb >= wqmax - WHALF) && (cb + 31 <= wqmin + WHALF);
                if (interior) {
                    #pragma unroll
                    for (int j = 0; j < 8; ++j)
                        p8s[j] = bf16bits(EXP2F(S[j >> 2][j & 3]));
                } else {
                    const int kbase = cb + 8 * g;
                    #pragma unroll
                    for (int j = 0; j < 8; ++j) {
                        int key = kbase + j;
                        bool valid = (key >= qrow - WHALF) && (key <= qrow + WHALF);
                        p8s[j] = bf16bits(EXP2F(valid ? S[j >> 2][j & 3] : -1e30f));
                    }
                }
                bf16x8 p8 = __builtin_bit_cast(bf16x8, p8s);

                __builtin_amdgcn_s_setprio(1);
                {
                    const int vc = kc * 32 + 8 * g;
                    bf16x8 xf0, xf1, xf2, xf3;
                    LDFRAG(xf0, &Vb[(n15) * VSTR + vc]);
                    LDFRAG(xf1, &Vb[(16 + n15) * VSTR + vc]);
                    LDFRAG(xf2, &Vb[(32 + n15) * VSTR + vc]);
                    LDFRAG(xf3, &Vb[(48 + n15) * VSTR + vc]);
                    accO0 = MFMA32(xf0, p8, accO0);
                    accO1 = MFMA32(xf1, p8, accO1);
                    accO2 = MFMA32(xf2, p8, accO2);
                    accO3 = MFMA32(xf3, p8, accO3);
                }
                accL = MFMA32(ones8, p8, accL);
                __builtin_amdgcn_s_setprio(0);
            }
        }

        if (i + 1 < nt) __syncthreads();   // next buffer staged by all waves
    }

    // ---- epilogue: lsum sits in accL[0] of the g=0 lane for each query ----
    const float lsum = __shfl(accL[0], n15);   // broadcast from lane id n15 (g=0 block)
    const float inv  = 1.0f / lsum;
    float* op = out + ((size_t)h * SEQ + qrow) * HD;
    *reinterpret_cast<f32x4*>(op + 0  + 4 * g) = accO0 * inv;
    *reinterpret_cast<f32x4*>(op + 16 + 4 * g) = accO1 * inv;
    *reinterpret_cast<f32x4*>(op + 32 + 4 * g) = accO2 * inv;
    *reinterpret_cast<f32x4*>(op + 48 + 4 * g) = accO3 * inv;
}

extern "C" void kernel_launch(void* const* d_in, const int* in_sizes, int n_in,
                              void* d_out, int out_size, void* d_ws, size_t ws_size,
                              hipStream_t stream) {
    const float* q = (const float*)d_in[0];
    const float* k = (const float*)d_in[1];
    const float* v = (const float*)d_in[2];
    float* out = (float*)d_out;

    dim3 grid(NH * (SEQ / QB));   // 512 blocks (1D for swizzle)
    dim3 block(512);              // 8 waves
    hipLaunchKernelGGL(swa_mfma14_kernel, grid, block, 0, stream, q, k, v, out);
}

// Round 15
// 26.591 us; speedup vs baseline: 2.2487x; 2.2487x over previous
//
#include <hip/hip_runtime.h>
#include <math.h>

#define SEQ   4096
#define HD    64
#define NH    16
#define WHALF 256
#define QB    128    // queries per block = 8 waves x 16
#define KT    128    // keys staged per barrier
#define KSTR  72     // K plane d-stride (shorts): 144B rows -> b128 R/W at 8-phase bank floor
#define VSTR  136    // V plane key-stride (shorts): 272B rows -> b128 R/W at 8-phase bank floor
#define KPLANE (KT * KSTR)   // 9216 shorts
#define VPLANE (HD * VSTR)   // 8704 shorts
#define BUFSZ  (KPLANE + VPLANE)

typedef __attribute__((ext_vector_type(8))) __bf16 bf16x8;
typedef __attribute__((ext_vector_type(8))) short short8v;
typedef __attribute__((ext_vector_type(4))) float f32x4;

__device__ __forceinline__ short bf16bits(float x) {
    __bf16 b = (__bf16)x;            // RTN
    return __builtin_bit_cast(short, b);
}

#define MFMA32(A, B, C) __builtin_amdgcn_mfma_f32_16x16x32_bf16((A), (B), (C), 0, 0, 0)

#if __has_builtin(__builtin_amdgcn_exp2f)
#define EXP2F(x) __builtin_amdgcn_exp2f(x)
#else
#define EXP2F(x) __exp2f(x)
#endif

#define LDFRAG(dst, src) (dst) = __builtin_bit_cast(bf16x8, *reinterpret_cast<const short8v*>(src))

__global__ __launch_bounds__(512, 4)
void swa_mfma15_kernel(const float* __restrict__ q,
                       const float* __restrict__ k,
                       const float* __restrict__ v,
                       float* __restrict__ out) {
    // double-buffered: [buf][K plane | V plane] ; 71680 B total -> 2 blocks/CU
    __shared__ short smem[2 * BUFSZ];

    // ---- XCD-aware bijective swizzle: 512 blocks = 8 XCDs x 64; head-major chunks ----
    const int orig = blockIdx.x;
    const int work = ((orig & 7) << 6) + (orig >> 3);
    const int h    = work >> 5;
    const int q0   = (work & 31) * QB;

    const int t    = threadIdx.x;
    const int lane = t & 63;
    const int w    = t >> 6;             // wave 0..7
    const int n15  = lane & 15;
    const int g    = lane >> 4;          // 0..3
    const int qrow = q0 + w * 16 + n15;  // this lane's query

    // scores in log2 domain (fold 1/sqrt(64)*log2(e) into Q); NO max-shift:
    // softmax is shift-invariant and scores are O(10) in the log2 domain.
    const float SCALE = 0.125f * 1.44269504088896340736f;

    // ---- Q fragments (B-operand of S^T = K·Q^T), pre-scaled, plain bf16 ----
    bf16x8 qf[2];
    {
        const float* qp = q + ((size_t)h * SEQ + qrow) * HD;
        #pragma unroll
        for (int c = 0; c < 2; ++c) {
            const float4* p4 = reinterpret_cast<const float4*>(qp + 32 * c + 8 * g);
            float4 a = p4[0], b = p4[1];
            float xs[8] = {a.x, a.y, a.z, a.w, b.x, b.y, b.z, b.w};
            short8v q8;
            #pragma unroll
            for (int j = 0; j < 8; ++j) q8[j] = bf16bits(xs[j] * SCALE);
            qf[c] = __builtin_bit_cast(bf16x8, q8);
        }
    }

    // ones A-fragment for the lsum MFMA (row 0 of A = ones): register constant
    bf16x8 ones8;
    {
        short8v o8;
        const short ov = (n15 == 0) ? (short)0x3F80 : (short)0;
        #pragma unroll
        for (int j = 0; j < 8; ++j) o8[j] = ov;
        ones8 = __builtin_bit_cast(bf16x8, o8);
    }

    f32x4 accO[4];
    #pragma unroll
    for (int dt = 0; dt < 4; ++dt) accO[dt] = (f32x4){0.f, 0.f, 0.f, 0.f};
    f32x4 accL = (f32x4){0.f, 0.f, 0.f, 0.f};   // lsum lands in reg 0 of g=0 lanes

    int k0 = q0 - WHALF;           if (k0 < 0) k0 = 0;
    int k1 = q0 + QB - 1 + WHALF;  if (k1 > SEQ - 1) k1 = SEQ - 1;
    const int nt = (k1 + 1 - k0) >> 7;   // whole 128-key tiles

    const int wqmin = q0 + w * 16;
    const int wqmax = wqmin + 15;
    const int wlo   = wqmin - WHALF;   // wave union window
    const int whi   = wqmax + WHALF;

    const float4* kb4 = reinterpret_cast<const float4*>(k + ((size_t)h * SEQ) * HD);
    const float*  vp  = v + ((size_t)h * SEQ) * HD;

    // ---- single-set 2-tile-deep register prefetch (R10-proven codegen form) ----
    float4 kreg[4];
    float  vreg[16];

    #define LOADT(KTV)                                                        \
        {                                                                     \
            const int kt_ = (KTV);                                            \
            _Pragma("unroll")                                                 \
            for (int i2 = 0; i2 < 4; ++i2)                                    \
                kreg[i2] = kb4[(size_t)kt_ * 16 + t * 4 + i2];                \
            _Pragma("unroll")                                                 \
            for (int j = 0; j < 16; ++j)                                      \
                vreg[j] = vp[(size_t)(kt_ + 16 * w + j) * HD + lane];         \
        }

    // ---- stage regs -> buffer b.  K rows PERMUTED (within each 32-key chunk)
    // so the QK D-fragment hands each lane keys 8g..8g+7 (K=32 PV B-order):
    // physical key p: R = (p & 96) | perm5(p & 31), perm5 validated since R7.
    auto STAGE = [&](int b) {
        short* Kb = smem + b * BUFSZ;
        short* Vb = Kb + KPLANE;

        const int p  = t >> 2;           // physical key row (0..127); 4 threads/row
        const int q5 = p & 31;
        const int R  = (p & 96) + (((q5 >> 2) & 1) << 4) + ((q5 >> 3) << 2) + (q5 & 3);

        const float* kf = reinterpret_cast<const float*>(&kreg[0]);
        short8v k8a, k8b;
        #pragma unroll
        for (int j = 0; j < 8; ++j) {
            k8a[j] = bf16bits(kf[j]);
            k8b[j] = bf16bits(kf[8 + j]);
        }
        *reinterpret_cast<short8v*>(&Kb[R * KSTR + (t & 3) * 16])     = k8a;
        *reinterpret_cast<short8v*>(&Kb[R * KSTR + (t & 3) * 16 + 8]) = k8b;

        short8v v8a, v8b;
        #pragma unroll
        for (int j = 0; j < 8; ++j) {
            v8a[j] = bf16bits(vreg[j]);
            v8b[j] = bf16bits(vreg[8 + j]);
        }
        *reinterpret_cast<short8v*>(&Vb[lane * VSTR + 16 * w])     = v8a;  // [d=lane][key 16w..]
        *reinterpret_cast<short8v*>(&Vb[lane * VSTR + 16 * w + 8]) = v8b;
    };

    LOADT(k0);
    STAGE(0);
    if (nt > 1) LOADT(k0 + KT);
    __syncthreads();

    for (int i = 0; i < nt; ++i) {
        const int kt  = k0 + i * KT;
        const int cur = i & 1;

        if (i + 1 < nt) {
            STAGE(cur ^ 1);
            if (i + 2 < nt) LOADT(k0 + (i + 2) * KT);
        }

        const short* Kb = smem + cur * BUFSZ;
        const short* Vb = Kb + KPLANE;

        const bool nomask = (kt >= wqmax - WHALF) && (kt + KT - 1 <= wqmin + WHALF);

        if (nomask) {
            #pragma unroll
            for (int kc = 0; kc < 4; ++kc) {
                // ---- issue ALL LDS reads for this chunk up front: K then V.
                // QK's MFMAs wait only the K reads (counted lgkmcnt); V's
                // latency lands under the exp2 block. ----
                const int krow0 = (kc * 32 + n15) * KSTR + 8 * g;
                const int krow1 = (kc * 32 + 16 + n15) * KSTR + 8 * g;
                bf16x8 k00, k01, k10, k11;
                LDFRAG(k00, &Kb[krow0]); LDFRAG(k01, &Kb[krow0 + 32]);
                LDFRAG(k10, &Kb[krow1]); LDFRAG(k11, &Kb[krow1 + 32]);

                const int vc = kc * 32 + 8 * g;
                bf16x8 xf0, xf1, xf2, xf3;
                LDFRAG(xf0, &Vb[(n15) * VSTR + vc]);
                LDFRAG(xf1, &Vb[(16 + n15) * VSTR + vc]);
                LDFRAG(xf2, &Vb[(32 + n15) * VSTR + vc]);
                LDFRAG(xf3, &Vb[(48 + n15) * VSTR + vc]);

                // ---- S^T = K·Q^T ----
                __builtin_amdgcn_s_setprio(1);
                f32x4 z = (f32x4){0.f, 0.f, 0.f, 0.f};
                f32x4 S0 = MFMA32(k00, qf[0], z); S0 = MFMA32(k01, qf[1], S0);
                f32x4 S1 = MFMA32(k10, qf[0], z); S1 = MFMA32(k11, qf[1], S1);
                __builtin_amdgcn_s_setprio(0);

                // P = exp2(S) — no masking; V reads complete underneath
                short8v p8s;
                p8s[0] = bf16bits(EXP2F(S0[0])); p8s[1] = bf16bits(EXP2F(S0[1]));
                p8s[2] = bf16bits(EXP2F(S0[2])); p8s[3] = bf16bits(EXP2F(S0[3]));
                p8s[4] = bf16bits(EXP2F(S1[0])); p8s[5] = bf16bits(EXP2F(S1[1]));
                p8s[6] = bf16bits(EXP2F(S1[2])); p8s[7] = bf16bits(EXP2F(S1[3]));
                bf16x8 p8 = __builtin_bit_cast(bf16x8, p8s);

                __builtin_amdgcn_s_setprio(1);
                accO[0] = MFMA32(xf0, p8, accO[0]);
                accO[1] = MFMA32(xf1, p8, accO[1]);
                accO[2] = MFMA32(xf2, p8, accO[2]);
                accO[3] = MFMA32(xf3, p8, accO[3]);
                accL    = MFMA32(ones8, p8, accL);
                __builtin_amdgcn_s_setprio(0);
            }
        } else {
            #pragma unroll
            for (int kc = 0; kc < 4; ++kc) {
                const int cb = kt + kc * 32;
                if (cb > whi || cb + 31 < wlo) continue;   // wave-uniform chunk skip

                // ---- issue K then V reads up front (same hoist as fast path) ----
                const int krow0 = (kc * 32 + n15) * KSTR + 8 * g;
                const int krow1 = (kc * 32 + 16 + n15) * KSTR + 8 * g;
                bf16x8 k00, k01, k10, k11;
                LDFRAG(k00, &Kb[krow0]); LDFRAG(k01, &Kb[krow0 + 32]);
                LDFRAG(k10, &Kb[krow1]); LDFRAG(k11, &Kb[krow1 + 32]);

                const int vc = kc * 32 + 8 * g;
                bf16x8 xf0, xf1, xf2, xf3;
                LDFRAG(xf0, &Vb[(n15) * VSTR + vc]);
                LDFRAG(xf1, &Vb[(16 + n15) * VSTR + vc]);
                LDFRAG(xf2, &Vb[(32 + n15) * VSTR + vc]);
                LDFRAG(xf3, &Vb[(48 + n15) * VSTR + vc]);

                // ---- S^T = K·Q^T ----
                __builtin_amdgcn_s_setprio(1);
                f32x4 z = (f32x4){0.f, 0.f, 0.f, 0.f};
                f32x4 S0 = MFMA32(k00, qf[0], z); S0 = MFMA32(k01, qf[1], S0);
                f32x4 S1 = MFMA32(k10, qf[0], z); S1 = MFMA32(k11, qf[1], S1);
                __builtin_amdgcn_s_setprio(0);

                // lane's 8 scores are keys cb+8g .. cb+8g+7
                // P = exp2(sc) directly (no shift); masked -> exp2(-1e30) == 0
                short8v p8s;
                const bool interior = (cb >= wqmax - WHALF) && (cb + 31 <= wqmin + WHALF);
                if (interior) {
                    p8s[0] = bf16bits(EXP2F(S0[0])); p8s[1] = bf16bits(EXP2F(S0[1]));
                    p8s[2] = bf16bits(EXP2F(S0[2])); p8s[3] = bf16bits(EXP2F(S0[3]));
                    p8s[4] = bf16bits(EXP2F(S1[0])); p8s[5] = bf16bits(EXP2F(S1[1]));
                    p8s[6] = bf16bits(EXP2F(S1[2])); p8s[7] = bf16bits(EXP2F(S1[3]));
                } else {
                    const int kbase = cb + 8 * g;
                    #pragma unroll
                    for (int j = 0; j < 8; ++j) {
                        int key = kbase + j;
                        bool valid = (key >= qrow - WHALF) && (key <= qrow + WHALF);
                        float sj = (j < 4) ? S0[j & 3] : S1[j & 3];
                        p8s[j] = bf16bits(EXP2F(valid ? sj : -1e30f));
                    }
                }
                bf16x8 p8 = __builtin_bit_cast(bf16x8, p8s);

                __builtin_amdgcn_s_setprio(1);
                accO[0] = MFMA32(xf0, p8, accO[0]);
                accO[1] = MFMA32(xf1, p8, accO[1]);
                accO[2] = MFMA32(xf2, p8, accO[2]);
                accO[3] = MFMA32(xf3, p8, accO[3]);
                accL    = MFMA32(ones8, p8, accL);
                __builtin_amdgcn_s_setprio(0);
            }
        }

        if (i + 1 < nt) __syncthreads();   // next buffer staged by all waves
    }

    // ---- epilogue: lsum sits in accL[0] of the g=0 lane for each query ----
    const float lsum = __shfl(accL[0], n15);   // broadcast from lane id n15 (g=0 block)
    const float inv  = 1.0f / lsum;
    float* op = out + ((size_t)h * SEQ + qrow) * HD;
    #pragma unroll
    for (int dt = 0; dt < 4; ++dt) {
        *reinterpret_cast<f32x4*>(op + dt * 16 + 4 * g) = accO[dt] * inv;
    }
}

extern "C" void kernel_launch(void* const* d_in, const int* in_sizes, int n_in,
                              void* d_out, int out_size, void* d_ws, size_t ws_size,
                              hipStream_t stream) {
    const float* q = (const float*)d_in[0];
    const float* k = (const float*)d_in[1];
    const float* v = (const float*)d_in[2];
    float* out = (float*)d_out;

    dim3 grid(NH * (SEQ / QB));   // 512 blocks (1D for swizzle)
    dim3 block(512);              // 8 waves
    hipLaunchKernelGGL(swa_mfma15_kernel, grid, block, 0, stream, q, k, v, out);
}

// Round 16
// 26.239 us; speedup vs baseline: 2.2790x; 1.0134x over previous
//
#include <hip/hip_runtime.h>
#include <math.h>

#define SEQ   4096
#define HD    64
#define NH    16
#define WHALF 256
#define QB    128    // queries per block = 8 waves x 16
#define KT    128    // keys staged per barrier
#define KSTR  72     // K plane d-stride (shorts): 144B rows -> b128 R/W at 8-phase bank floor
#define VSTR  136    // V plane key-stride (shorts): 272B rows -> b128 R/W at 8-phase bank floor
#define KPLANE (KT * KSTR)   // 9216 shorts
#define VPLANE (HD * VSTR)   // 8704 shorts
#define BUFSZ  (KPLANE + VPLANE)

typedef __attribute__((ext_vector_type(8))) __bf16 bf16x8;
typedef __attribute__((ext_vector_type(8))) short short8v;
typedef __attribute__((ext_vector_type(4))) float f32x4;

__device__ __forceinline__ short bf16bits(float x) {
    __bf16 b = (__bf16)x;            // RTN
    return __builtin_bit_cast(short, b);
}

#define MFMA32(A, B, C) __builtin_amdgcn_mfma_f32_16x16x32_bf16((A), (B), (C), 0, 0, 0)

#if __has_builtin(__builtin_amdgcn_exp2f)
#define EXP2F(x) __builtin_amdgcn_exp2f(x)
#else
#define EXP2F(x) __exp2f(x)
#endif

#define LDFRAG(dst, src) (dst) = __builtin_bit_cast(bf16x8, *reinterpret_cast<const short8v*>(src))

// launch_bounds second arg is MIN BLOCKS PER CU (CUDA semantics): 4 was
// forcing a 32-wave/CU target -> 64-VGPR cap -> allocator starvation +
// scratch spills (R11/R14) even though the 512-block grid only ever puts
// 2 blocks/CU. Bound 2 -> 16 waves/CU target -> 128-VGPR budget.
__global__ __launch_bounds__(512, 2)
void swa_mfma16_kernel(const float* __restrict__ q,
                       const float* __restrict__ k,
                       const float* __restrict__ v,
                       float* __restrict__ out) {
    // double-buffered: [buf][K plane | V plane] ; 71680 B total -> 2 blocks/CU
    __shared__ short smem[2 * BUFSZ];

    // ---- XCD-aware bijective swizzle: 512 blocks = 8 XCDs x 64; head-major chunks ----
    const int orig = blockIdx.x;
    const int work = ((orig & 7) << 6) + (orig >> 3);
    const int h    = work >> 5;
    const int q0   = (work & 31) * QB;

    const int t    = threadIdx.x;
    const int lane = t & 63;
    const int w    = t >> 6;             // wave 0..7
    const int n15  = lane & 15;
    const int g    = lane >> 4;          // 0..3
    const int qrow = q0 + w * 16 + n15;  // this lane's query

    // scores in log2 domain (fold 1/sqrt(64)*log2(e) into Q); NO max-shift:
    // softmax is shift-invariant and scores are O(10) in the log2 domain.
    const float SCALE = 0.125f * 1.44269504088896340736f;

    // ---- Q fragments (B-operand of S^T = K·Q^T), pre-scaled, plain bf16 ----
    bf16x8 qf[2];
    {
        const float* qp = q + ((size_t)h * SEQ + qrow) * HD;
        #pragma unroll
        for (int c = 0; c < 2; ++c) {
            const float4* p4 = reinterpret_cast<const float4*>(qp + 32 * c + 8 * g);
            float4 a = p4[0], b = p4[1];
            float xs[8] = {a.x, a.y, a.z, a.w, b.x, b.y, b.z, b.w};
            short8v q8;
            #pragma unroll
            for (int j = 0; j < 8; ++j) q8[j] = bf16bits(xs[j] * SCALE);
            qf[c] = __builtin_bit_cast(bf16x8, q8);
        }
    }

    // ones A-fragment for the lsum MFMA (row 0 of A = ones): register constant
    bf16x8 ones8;
    {
        short8v o8;
        const short ov = (n15 == 0) ? (short)0x3F80 : (short)0;
        #pragma unroll
        for (int j = 0; j < 8; ++j) o8[j] = ov;
        ones8 = __builtin_bit_cast(bf16x8, o8);
    }

    f32x4 accO[4];
    #pragma unroll
    for (int dt = 0; dt < 4; ++dt) accO[dt] = (f32x4){0.f, 0.f, 0.f, 0.f};
    f32x4 accL = (f32x4){0.f, 0.f, 0.f, 0.f};   // lsum lands in reg 0 of g=0 lanes

    int k0 = q0 - WHALF;           if (k0 < 0) k0 = 0;
    int k1 = q0 + QB - 1 + WHALF;  if (k1 > SEQ - 1) k1 = SEQ - 1;
    const int nt = (k1 + 1 - k0) >> 7;   // whole 128-key tiles

    const int wqmin = q0 + w * 16;
    const int wqmax = wqmin + 15;
    const int wlo   = wqmin - WHALF;   // wave union window
    const int whi   = wqmax + WHALF;

    const float4* kb4 = reinterpret_cast<const float4*>(k + ((size_t)h * SEQ) * HD);
    const float*  vp  = v + ((size_t)h * SEQ) * HD;

    // ---- single-set 2-tile-deep register prefetch (R10-proven codegen form) ----
    float4 kreg[4];
    float  vreg[16];

    #define LOADT(KTV)                                                        \
        {                                                                     \
            const int kt_ = (KTV);                                            \
            _Pragma("unroll")                                                 \
            for (int i2 = 0; i2 < 4; ++i2)                                    \
                kreg[i2] = kb4[(size_t)kt_ * 16 + t * 4 + i2];                \
            _Pragma("unroll")                                                 \
            for (int j = 0; j < 16; ++j)                                      \
                vreg[j] = vp[(size_t)(kt_ + 16 * w + j) * HD + lane];         \
        }

    // ---- stage regs -> buffer b.  K rows PERMUTED (within each 32-key chunk)
    // so the QK D-fragment hands each lane keys 8g..8g+7 (K=32 PV B-order):
    // physical key p: R = (p & 96) | perm5(p & 31), perm5 validated since R7.
    auto STAGE = [&](int b) {
        short* Kb = smem + b * BUFSZ;
        short* Vb = Kb + KPLANE;

        const int p  = t >> 2;           // physical key row (0..127); 4 threads/row
        const int q5 = p & 31;
        const int R  = (p & 96) + (((q5 >> 2) & 1) << 4) + ((q5 >> 3) << 2) + (q5 & 3);

        const float* kf = reinterpret_cast<const float*>(&kreg[0]);
        short8v k8a, k8b;
        #pragma unroll
        for (int j = 0; j < 8; ++j) {
            k8a[j] = bf16bits(kf[j]);
            k8b[j] = bf16bits(kf[8 + j]);
        }
        *reinterpret_cast<short8v*>(&Kb[R * KSTR + (t & 3) * 16])     = k8a;
        *reinterpret_cast<short8v*>(&Kb[R * KSTR + (t & 3) * 16 + 8]) = k8b;

        short8v v8a, v8b;
        #pragma unroll
        for (int j = 0; j < 8; ++j) {
            v8a[j] = bf16bits(vreg[j]);
            v8b[j] = bf16bits(vreg[8 + j]);
        }
        *reinterpret_cast<short8v*>(&Vb[lane * VSTR + 16 * w])     = v8a;  // [d=lane][key 16w..]
        *reinterpret_cast<short8v*>(&Vb[lane * VSTR + 16 * w + 8]) = v8b;
    };

    LOADT(k0);
    STAGE(0);
    if (nt > 1) LOADT(k0 + KT);
    __syncthreads();

    for (int i = 0; i < nt; ++i) {
        const int kt  = k0 + i * KT;
        const int cur = i & 1;

        if (i + 1 < nt) {
            STAGE(cur ^ 1);
            if (i + 2 < nt) LOADT(k0 + (i + 2) * KT);
        }

        const short* Kb = smem + cur * BUFSZ;
        const short* Vb = Kb + KPLANE;

        const bool nomask = (kt >= wqmax - WHALF) && (kt + KT - 1 <= wqmin + WHALF);

        if (nomask) {
            #pragma unroll
            for (int kc = 0; kc < 4; ++kc) {
                // ---- issue ALL LDS reads for this chunk up front: K then V.
                // QK's MFMAs wait only the K reads (counted lgkmcnt); V's
                // latency lands under the exp2 block. ----
                const int krow0 = (kc * 32 + n15) * KSTR + 8 * g;
                const int krow1 = (kc * 32 + 16 + n15) * KSTR + 8 * g;
                bf16x8 k00, k01, k10, k11;
                LDFRAG(k00, &Kb[krow0]); LDFRAG(k01, &Kb[krow0 + 32]);
                LDFRAG(k10, &Kb[krow1]); LDFRAG(k11, &Kb[krow1 + 32]);

                const int vc = kc * 32 + 8 * g;
                bf16x8 xf0, xf1, xf2, xf3;
                LDFRAG(xf0, &Vb[(n15) * VSTR + vc]);
                LDFRAG(xf1, &Vb[(16 + n15) * VSTR + vc]);
                LDFRAG(xf2, &Vb[(32 + n15) * VSTR + vc]);
                LDFRAG(xf3, &Vb[(48 + n15) * VSTR + vc]);

                // ---- S^T = K·Q^T ----
                __builtin_amdgcn_s_setprio(1);
                f32x4 z = (f32x4){0.f, 0.f, 0.f, 0.f};
                f32x4 S0 = MFMA32(k00, qf[0], z); S0 = MFMA32(k01, qf[1], S0);
                f32x4 S1 = MFMA32(k10, qf[0], z); S1 = MFMA32(k11, qf[1], S1);
                __builtin_amdgcn_s_setprio(0);

                // P = exp2(S) — no masking; V reads complete underneath
                short8v p8s;
                p8s[0] = bf16bits(EXP2F(S0[0])); p8s[1] = bf16bits(EXP2F(S0[1]));
                p8s[2] = bf16bits(EXP2F(S0[2])); p8s[3] = bf16bits(EXP2F(S0[3]));
                p8s[4] = bf16bits(EXP2F(S1[0])); p8s[5] = bf16bits(EXP2F(S1[1]));
                p8s[6] = bf16bits(EXP2F(S1[2])); p8s[7] = bf16bits(EXP2F(S1[3]));
                bf16x8 p8 = __builtin_bit_cast(bf16x8, p8s);

                __builtin_amdgcn_s_setprio(1);
                accO[0] = MFMA32(xf0, p8, accO[0]);
                accO[1] = MFMA32(xf1, p8, accO[1]);
                accO[2] = MFMA32(xf2, p8, accO[2]);
                accO[3] = MFMA32(xf3, p8, accO[3]);
                accL    = MFMA32(ones8, p8, accL);
                __builtin_amdgcn_s_setprio(0);
            }
        } else {
            #pragma unroll
            for (int kc = 0; kc < 4; ++kc) {
                const int cb = kt + kc * 32;
                if (cb > whi || cb + 31 < wlo) continue;   // wave-uniform chunk skip

                // ---- issue K then V reads up front (same hoist as fast path) ----
                const int krow0 = (kc * 32 + n15) * KSTR + 8 * g;
                const int krow1 = (kc * 32 + 16 + n15) * KSTR + 8 * g;
                bf16x8 k00, k01, k10, k11;
                LDFRAG(k00, &Kb[krow0]); LDFRAG(k01, &Kb[krow0 + 32]);
                LDFRAG(k10, &Kb[krow1]); LDFRAG(k11, &Kb[krow1 + 32]);

                const int vc = kc * 32 + 8 * g;
                bf16x8 xf0, xf1, xf2, xf3;
                LDFRAG(xf0, &Vb[(n15) * VSTR + vc]);
                LDFRAG(xf1, &Vb[(16 + n15) * VSTR + vc]);
                LDFRAG(xf2, &Vb[(32 + n15) * VSTR + vc]);
                LDFRAG(xf3, &Vb[(48 + n15) * VSTR + vc]);

                // ---- S^T = K·Q^T ----
                __builtin_amdgcn_s_setprio(1);
                f32x4 z = (f32x4){0.f, 0.f, 0.f, 0.f};
                f32x4 S0 = MFMA32(k00, qf[0], z); S0 = MFMA32(k01, qf[1], S0);
                f32x4 S1 = MFMA32(k10, qf[0], z); S1 = MFMA32(k11, qf[1], S1);
                __builtin_amdgcn_s_setprio(0);

                // lane's 8 scores are keys cb+8g .. cb+8g+7
                // P = exp2(sc) directly (no shift); masked -> exp2(-1e30) == 0
                short8v p8s;
                const bool interior = (cb >= wqmax - WHALF) && (cb + 31 <= wqmin + WHALF);
                if (interior) {
                    p8s[0] = bf16bits(EXP2F(S0[0])); p8s[1] = bf16bits(EXP2F(S0[1]));
                    p8s[2] = bf16bits(EXP2F(S0[2])); p8s[3] = bf16bits(EXP2F(S0[3]));
                    p8s[4] = bf16bits(EXP2F(S1[0])); p8s[5] = bf16bits(EXP2F(S1[1]));
                    p8s[6] = bf16bits(EXP2F(S1[2])); p8s[7] = bf16bits(EXP2F(S1[3]));
                } else {
                    const int kbase = cb + 8 * g;
                    #pragma unroll
                    for (int j = 0; j < 8; ++j) {
                        int key = kbase + j;
                        bool valid = (key >= qrow - WHALF) && (key <= qrow + WHALF);
                        float sj = (j < 4) ? S0[j & 3] : S1[j & 3];
                        p8s[j] = bf16bits(EXP2F(valid ? sj : -1e30f));
                    }
                }
                bf16x8 p8 = __builtin_bit_cast(bf16x8, p8s);

                __builtin_amdgcn_s_setprio(1);
                accO[0] = MFMA32(xf0, p8, accO[0]);
                accO[1] = MFMA32(xf1, p8, accO[1]);
                accO[2] = MFMA32(xf2, p8, accO[2]);
                accO[3] = MFMA32(xf3, p8, accO[3]);
                accL    = MFMA32(ones8, p8, accL);
                __builtin_amdgcn_s_setprio(0);
            }
        }

        if (i + 1 < nt) __syncthreads();   // next buffer staged by all waves
    }

    // ---- epilogue: lsum sits in accL[0] of the g=0 lane for each query ----
    const float lsum = __shfl(accL[0], n15);   // broadcast from lane id n15 (g=0 block)
    const float inv  = 1.0f / lsum;
    float* op = out + ((size_t)h * SEQ + qrow) * HD;
    #pragma unroll
    for (int dt = 0; dt < 4; ++dt) {
        *reinterpret_cast<f32x4*>(op + dt * 16 + 4 * g) = accO[dt] * inv;
    }
}

extern "C" void kernel_launch(void* const* d_in, const int* in_sizes, int n_in,
                              void* d_out, int out_size, void* d_ws, size_t ws_size,
                              hipStream_t stream) {
    const float* q = (const float*)d_in[0];
    const float* k = (const float*)d_in[1];
    const float* v = (const float*)d_in[2];
    float* out = (float*)d_out;

    dim3 grid(NH * (SEQ / QB));   // 512 blocks (1D for swizzle)
    dim3 block(512);              // 8 waves
    hipLaunchKernelGGL(swa_mfma16_kernel, grid, block, 0, stream, q, k, v, out);
}